// Round 5
// baseline (255.361 us; speedup 1.0000x reference)
//
#include <hip/hip_runtime.h>
#include <hip/hip_bf16.h>
#include <math.h>

#define HID 4096
#define R_TOTAL 16384

typedef __attribute__((ext_vector_type(8))) short short8;
typedef __attribute__((ext_vector_type(8))) unsigned short ushort8;
typedef __attribute__((ext_vector_type(4))) float f32x4;

__device__ __forceinline__ ushort bfc(float f) {
  __hip_bfloat16 h = __float2bfloat16(f);
  return *(ushort*)&h;
}

// ---------------------------------------------------------------------------
// Prep: w1T bf16 [32][4096] (col-major of w1), w4T bf16 [4096][32]
// (transpose of w4), and coupled[16] -> cpl[0..15].
// ---------------------------------------------------------------------------
__global__ __launch_bounds__(256) void wn_prep(
    const float* __restrict__ w1, const float* __restrict__ w4,
    ushort* __restrict__ w1T, ushort* __restrict__ w4T,
    const float* __restrict__ freq, const float* __restrict__ phases,
    const float* __restrict__ coupling, const float* __restrict__ damping,
    const float* __restrict__ tstep, float* __restrict__ cpl)
{
  __shared__ ushort tile[64*72];
  __shared__ float base[16];
  const int b = blockIdx.x, t = threadIdx.x;
  if (b < 64) {                      // w1T chunk: k in [b*64, b*64+64)
    #pragma unroll
    for (int i = 0; i < 8; ++i) {
      const int e = t + i*256, kk = e >> 5, c = e & 31;
      tile[c*72 + kk] = bfc(w1[(size_t)(b*64+kk)*32 + c]);
    }
    __syncthreads();
    const int c = t >> 3, j = t & 7;
    ushort8 v;
    #pragma unroll
    for (int q = 0; q < 8; ++q) v[q] = tile[c*72 + j*8 + q];
    *(ushort8*)&w1T[(size_t)c*HID + b*64 + j*8] = v;
  } else if (b < 128) {              // w4T chunk: h in [b2*64, b2*64+64)
    const int b2 = b - 64;
    #pragma unroll
    for (int i = 0; i < 8; ++i) {
      const int e = t + i*256, d = e >> 6, hh = e & 63;
      tile[hh*40 + d] = bfc(w4[(size_t)d*HID + b2*64 + hh]);
    }
    __syncthreads();
    const int hh = t >> 2, j = t & 3;
    ushort8 v;
    #pragma unroll
    for (int q = 0; q < 8; ++q) v[q] = tile[hh*40 + j*8 + q];
    *(ushort8*)&w4T[(size_t)(b2*64+hh)*32 + j*8] = v;
  } else {                           // coupled
    const float tt = tstep[0] + 0.1f;
    if (t < 16)
      base[t] = sinf(6.283185307179586f*freq[t]*tt + phases[t]) * expf(-damping[t]*tt);
    __syncthreads();
    if (t < 16) {
      float s = 0.f;
      #pragma unroll
      for (int i = 0; i < 16; ++i) s += base[i]*coupling[i*16+t];
      cpl[t] = tanhf(s);
    }
  }
}

// ---------------------------------------------------------------------------
// Phase 1 v2 (barrier-free MFMA): x@w1 -> LN -> SiLU -> @w2 -> mod -> @w3
//   -> LN -> SiLU -> o(bf16).
// 512 blocks x 512 thr (8 waves). 32 rows/block. Wave w: m-tile (w&1),
// K-quarter (w>>2... w>>1 in [0,4)). A-frags loaded DIRECTLY from global x
// (8 consecutive k per lane = float4 x2), B-frags from L2-resident w1T.
// No __syncthreads in the K loop; one LDS reduce of 4 K-partials at the end.
// ---------------------------------------------------------------------------
__global__ __launch_bounds__(512, 4) void wn_phase1(
    const float* __restrict__ x, const ushort* __restrict__ w1T,
    const float* __restrict__ b1, const float* __restrict__ g1,
    const float* __restrict__ beta1, const float* __restrict__ w2,
    const float* __restrict__ b2, const float* __restrict__ w3,
    const float* __restrict__ b3, const float* __restrict__ g2,
    const float* __restrict__ beta2, const float* __restrict__ cpl,
    ushort* __restrict__ o_ws, float* __restrict__ gacc)
{
  __shared__ __align__(16) float lds[6720];
  float* red  = lds;           // [8 waves][8 j][64 lane] = 4096
  float* yl   = lds + 4096;    // [32][33] = 1056
  float* w2l  = lds + 5152;    // [32][16] = 512
  float* w3l  = lds + 5664;    // [16][32] = 512
  float* msum = lds + 6176;    // [32][17] = 544
  const int t  = threadIdx.x;
  const int r0 = blockIdx.x * 32;

  if (t < 128) *(float4*)&w2l[t*4] = *(const float4*)&w2[t*4];
  else if (t < 256) { const int u2 = t-128; *(float4*)&w3l[u2*4] = *(const float4*)&w3[u2*4]; }

  const int w  = t >> 6, l = t & 63;
  const int mt = w & 1, kh = w >> 1;          // K-quarter 0..3
  const int lr = l & 15, lk = l >> 4;
  const int row = r0 + mt*16 + lr;
  const size_t xbase = (size_t)row*HID + kh*1024 + lk*8;
  const ushort* bp0 = &w1T[(size_t)lr*HID + kh*1024 + lk*8];
  const ushort* bp1 = bp0 + 16*HID;

  f32x4 acc0 = {0.f,0.f,0.f,0.f}, acc1 = {0.f,0.f,0.f,0.f};
  float4 a0 = *(const float4*)&x[xbase];
  float4 a1 = *(const float4*)&x[xbase + 4];
  short8 b0 = *(const short8*)bp0;
  short8 b1v = *(const short8*)bp1;

  for (int it = 0; it < 32; ++it) {
    float4 na0, na1; short8 nb0, nb1;
    if (it < 31) {
      const int ko = (it+1)*32;
      na0 = *(const float4*)&x[xbase + ko];
      na1 = *(const float4*)&x[xbase + ko + 4];
      nb0 = *(const short8*)(bp0 + ko);
      nb1 = *(const short8*)(bp1 + ko);
    }
    short8 av;
    av[0] = (short)bfc(a0.x); av[1] = (short)bfc(a0.y);
    av[2] = (short)bfc(a0.z); av[3] = (short)bfc(a0.w);
    av[4] = (short)bfc(a1.x); av[5] = (short)bfc(a1.y);
    av[6] = (short)bfc(a1.z); av[7] = (short)bfc(a1.w);
    acc0 = __builtin_amdgcn_mfma_f32_16x16x32_bf16(av, b0, acc0, 0, 0, 0);
    acc1 = __builtin_amdgcn_mfma_f32_16x16x32_bf16(av, b1v, acc1, 0, 0, 0);
    a0 = na0; a1 = na1; b0 = nb0; b1v = nb1;
  }
  // write K-partials (lane-consecutive layout: conflict-free scalar stores)
  {
    float* rp = &red[w*512 + l];
    #pragma unroll
    for (int j = 0; j < 4; ++j) { rp[j*64] = acc0[j]; rp[(4+j)*64] = acc1[j]; }
  }
  __syncthreads();
  if (t < 128) {   // reduce 4 K-quarters -> yl[32][33]
    const int m2 = t >> 6, l2 = t & 63;
    const int rr = m2*16 + (l2 >> 4)*4, cc = l2 & 15;
    #pragma unroll
    for (int j = 0; j < 4; ++j) {
      float s0 = 0.f, s1 = 0.f;
      #pragma unroll
      for (int k = 0; k < 4; ++k) {
        s0 += red[(m2 + 2*k)*512 + j*64 + l2];
        s1 += red[(m2 + 2*k)*512 + (4+j)*64 + l2];
      }
      yl[(rr+j)*33 + cc]      = s0;
      yl[(rr+j)*33 + 16 + cc] = s1;
    }
  }
  __syncthreads();
  // fused epilogue: 4 threads/row (32 rows)
  if (t < 128) {
    const int row2 = t >> 2, q = t & 3, d0 = q*8;
    float v[8]; float mu = 0.f;
    #pragma unroll
    for (int dd = 0; dd < 8; ++dd) { v[dd] = yl[row2*33 + d0+dd] + b1[d0+dd]; mu += v[dd]; }
    mu += __shfl_xor(mu,1); mu += __shfl_xor(mu,2); mu *= (1.f/32.f);
    float var = 0.f;
    #pragma unroll
    for (int dd = 0; dd < 8; ++dd) { const float c = v[dd]-mu; var += c*c; }
    var += __shfl_xor(var,1); var += __shfl_xor(var,2);
    const float rs = rsqrtf(var*(1.f/32.f) + 1e-5f);
    float wiv[16];
    #pragma unroll
    for (int ww = 0; ww < 16; ++ww) wiv[ww] = 0.f;
    #pragma unroll
    for (int dd = 0; dd < 8; ++dd) {
      const float hn = (v[dd]-mu)*rs*g1[d0+dd] + beta1[d0+dd];
      const float sl = hn / (1.f + __expf(-hn));
      const float* wr = &w2l[(d0+dd)*16];
      #pragma unroll
      for (int ww = 0; ww < 16; ++ww) wiv[ww] = fmaf(sl, wr[ww], wiv[ww]);
    }
    #pragma unroll
    for (int ww = 0; ww < 16; ++ww) {
      wiv[ww] += __shfl_xor(wiv[ww],1);
      wiv[ww] += __shfl_xor(wiv[ww],2);
    }
    float mod[16];
    #pragma unroll
    for (int ww = 0; ww < 16; ++ww) mod[ww] = cpl[ww]*(1.f + wiv[ww] + b2[ww]);
    #pragma unroll
    for (int j = 0; j < 4; ++j) msum[row2*17 + q*4+j] = mod[q*4+j];
    float p[8];
    #pragma unroll
    for (int dd = 0; dd < 8; ++dd) p[dd] = b3[d0+dd];
    #pragma unroll
    for (int ww = 0; ww < 16; ++ww) {
      const float m = mod[ww];
      const float* wr = &w3l[ww*32 + d0];
      #pragma unroll
      for (int dd = 0; dd < 8; ++dd) p[dd] = fmaf(m, wr[dd], p[dd]);
    }
    float mu2 = 0.f;
    #pragma unroll
    for (int dd = 0; dd < 8; ++dd) mu2 += p[dd];
    mu2 += __shfl_xor(mu2,1); mu2 += __shfl_xor(mu2,2); mu2 *= (1.f/32.f);
    float var2 = 0.f;
    #pragma unroll
    for (int dd = 0; dd < 8; ++dd) { const float c = p[dd]-mu2; var2 += c*c; }
    var2 += __shfl_xor(var2,1); var2 += __shfl_xor(var2,2);
    const float rs2 = rsqrtf(var2*(1.f/32.f) + 1e-5f);
    ushort8 ov;
    #pragma unroll
    for (int dd = 0; dd < 8; ++dd) {
      const float hn = (p[dd]-mu2)*rs2*g2[d0+dd] + beta2[d0+dd];
      ov[dd] = bfc(hn / (1.f + __expf(-hn)));
    }
    *(ushort8*)&o_ws[(size_t)(r0+row2)*32 + d0] = ov;
  }
  __syncthreads();
  if (t < 16) {
    float s = 0.f;
    for (int r = 0; r < 32; ++r) s += msum[r*17 + t];
    atomicAdd(gacc + t, s);
  }
}

// ---------------------------------------------------------------------------
// Phase 2: resonance_factor -> cpl[16]
// ---------------------------------------------------------------------------
__global__ void wn_phase2(const float* __restrict__ gacc, float* __restrict__ cpl)
{
  __shared__ float res[16];
  const int t = threadIdx.x;
  if (t < 16) res[t] = 0.1f * fabsf(gacc[t] * (1.f/(float)R_TOTAL));
  __syncthreads();
  if (t == 0) {
    float s = 0.f;
    #pragma unroll
    for (int ww = 0; ww < 16; ++ww) s += res[ww];
    cpl[16] = 1.f / (1.f + expf(-s*(1.f/16.f)));
  }
}

// ---------------------------------------------------------------------------
// Phase 3 (MFMA swapped-operand, zero LDS): out = x + rf*(o@w4 + b4).
// A = w4T rows (n-dim), B = o rows (m-dim) -> C[row=n][col=m]: each lane owns
// 4 CONSECUTIVE n for its fixed m -> float4 x-load/out-store (full 64B lines).
// 2048 blocks (256 row-blks x 8 strips) x 256 thr; wave = one 16-row m-tile.
// ---------------------------------------------------------------------------
__global__ __launch_bounds__(256) void wn_phase3(
    const float* __restrict__ x, const ushort* __restrict__ o_bf,
    const ushort* __restrict__ w4T, const float* __restrict__ b4,
    const float* __restrict__ cpl, float* __restrict__ out)
{
  const int t = threadIdx.x, l = t & 63, w = t >> 6;
  const int bid = blockIdx.x;
  const int strip = bid & 7, m0 = (bid >> 3) * 64 + w*16;
  const float rf = cpl[16];
  const int lm = l & 15, lkb = l >> 4;
  // B-frag: o rows (col operand, m): col=lane&15, k=(lane>>4)*8..+7
  const short8 bv = *(const short8*)&o_bf[(size_t)(m0+lm)*32 + lkb*8];
  const int mrow = m0 + lm;            // this lane's output row
  const size_t rowbase = (size_t)mrow*HID + strip*512 + lkb*4;
  #pragma unroll 4
  for (int nt = 0; nt < 32; ++nt) {
    const int n0 = strip*512 + nt*16;
    // A-frag: w4T rows (row operand, n): row=lane&15, k=(lane>>4)*8..+7
    const short8 av = *(const short8*)&w4T[(size_t)(n0+lm)*32 + lkb*8];
    f32x4 c = {0.f,0.f,0.f,0.f};
    c = __builtin_amdgcn_mfma_f32_16x16x32_bf16(av, bv, c, 0, 0, 0);
    // lane owns C rows n0+lkb*4..+3 (consecutive n), col m = mrow
    const size_t off = rowbase + (size_t)nt*16;
    const float4 xv  = *(const float4*)&x[off];
    const float4 b4v = *(const float4*)&b4[n0 + lkb*4];
    float4 o2;
    o2.x = fmaf(rf, c[0] + b4v.x, xv.x);
    o2.y = fmaf(rf, c[1] + b4v.y, xv.y);
    o2.z = fmaf(rf, c[2] + b4v.z, xv.z);
    o2.w = fmaf(rf, c[3] + b4v.w, xv.w);
    *(float4*)&out[off] = o2;
  }
}

extern "C" void kernel_launch(void* const* d_in, const int* in_sizes, int n_in,
                              void* d_out, int out_size, void* d_ws, size_t ws_size,
                              hipStream_t stream) {
  const float* x        = (const float*)d_in[0];
  const float* freq     = (const float*)d_in[1];
  const float* phases   = (const float*)d_in[2];
  const float* coupling = (const float*)d_in[3];
  const float* damping  = (const float*)d_in[4];
  const float* w1       = (const float*)d_in[5];
  const float* b1       = (const float*)d_in[6];
  const float* g1       = (const float*)d_in[7];
  const float* beta1    = (const float*)d_in[8];
  const float* w2       = (const float*)d_in[9];
  const float* b2       = (const float*)d_in[10];
  const float* w3       = (const float*)d_in[11];
  const float* b3       = (const float*)d_in[12];
  const float* g2       = (const float*)d_in[13];
  const float* beta2    = (const float*)d_in[14];
  const float* w4       = (const float*)d_in[15];
  const float* b4       = (const float*)d_in[16];
  const float* tstep    = (const float*)d_in[17];
  float* out = (float*)d_out;

  char* wsb = (char*)d_ws;
  ushort* o_bf = (ushort*)wsb;                        // 1 MiB
  ushort* w1T  = (ushort*)(wsb + (1<<20));            // 256 KiB
  ushort* w4T  = (ushort*)(wsb + (1<<20) + (256<<10));// 256 KiB
  float*  gacc = (float*)(wsb + (1<<20) + (512<<10)); // 64 B
  float*  cpl  = gacc + 16;                           // 17 floats

  hipMemsetAsync(gacc, 0, 16*sizeof(float), stream);
  hipLaunchKernelGGL(wn_prep, dim3(129), dim3(256), 0, stream,
                     w1, w4, w1T, w4T, freq, phases, coupling, damping, tstep, cpl);
  hipLaunchKernelGGL(wn_phase1, dim3(512), dim3(512), 0, stream,
                     x, w1T, b1, g1, beta1, w2, b2, w3, b3, g2, beta2, cpl, o_bf, gacc);
  hipLaunchKernelGGL(wn_phase2, dim3(1), dim3(64), 0, stream, gacc, cpl);
  hipLaunchKernelGGL(wn_phase3, dim3(2048), dim3(256), 0, stream,
                     x, o_bf, w4T, b4, cpl, out);
}

// Round 7
// 227.608 us; speedup vs baseline: 1.1219x; 1.1219x over previous
//
#include <hip/hip_runtime.h>
#include <hip/hip_bf16.h>
#include <math.h>

#define HID 4096
#define R_TOTAL 16384

typedef __attribute__((ext_vector_type(8))) short short8;
typedef __attribute__((ext_vector_type(8))) unsigned short ushort8;
typedef __attribute__((ext_vector_type(4))) float f32x4;

__device__ __forceinline__ ushort bfc(float f) {
  __hip_bfloat16 h = __float2bfloat16(f);
  return *(ushort*)&h;
}

// ---------------------------------------------------------------------------
// Prep: w1T bf16 [32][4096] (col-major of w1), w4T bf16 [4096][32]
// (transpose of w4), and coupled[16] -> cpl[0..15].
// ---------------------------------------------------------------------------
__global__ __launch_bounds__(256) void wn_prep(
    const float* __restrict__ w1, const float* __restrict__ w4,
    ushort* __restrict__ w1T, ushort* __restrict__ w4T,
    const float* __restrict__ freq, const float* __restrict__ phases,
    const float* __restrict__ coupling, const float* __restrict__ damping,
    const float* __restrict__ tstep, float* __restrict__ cpl)
{
  __shared__ ushort tile[64*72];
  __shared__ float base[16];
  const int b = blockIdx.x, t = threadIdx.x;
  if (b < 64) {                      // w1T chunk: k in [b*64, b*64+64)
    #pragma unroll
    for (int i = 0; i < 8; ++i) {
      const int e = t + i*256, kk = e >> 5, c = e & 31;
      tile[c*72 + kk] = bfc(w1[(size_t)(b*64+kk)*32 + c]);
    }
    __syncthreads();
    const int c = t >> 3, j = t & 7;
    ushort8 v;
    #pragma unroll
    for (int q = 0; q < 8; ++q) v[q] = tile[c*72 + j*8 + q];
    *(ushort8*)&w1T[(size_t)c*HID + b*64 + j*8] = v;
  } else if (b < 128) {              // w4T chunk: h in [b2*64, b2*64+64)
    const int b2 = b - 64;
    #pragma unroll
    for (int i = 0; i < 8; ++i) {
      const int e = t + i*256, d = e >> 6, hh = e & 63;
      tile[hh*40 + d] = bfc(w4[(size_t)d*HID + b2*64 + hh]);
    }
    __syncthreads();
    const int hh = t >> 2, j = t & 3;
    ushort8 v;
    #pragma unroll
    for (int q = 0; q < 8; ++q) v[q] = tile[hh*40 + j*8 + q];
    *(ushort8*)&w4T[(size_t)(b2*64+hh)*32 + j*8] = v;
  } else {                           // coupled
    const float tt = tstep[0] + 0.1f;
    if (t < 16)
      base[t] = sinf(6.283185307179586f*freq[t]*tt + phases[t]) * expf(-damping[t]*tt);
    __syncthreads();
    if (t < 16) {
      float s = 0.f;
      #pragma unroll
      for (int i = 0; i < 16; ++i) s += base[i]*coupling[i*16+t];
      cpl[t] = tanhf(s);
    }
  }
}

// ---------------------------------------------------------------------------
// Phase 1 (MFMA, R4 version): y = x@w1 -> LN -> SiLU -> @w2 -> mod -> @w3
//   -> LN -> SiLU -> o(bf16).
// 512 blocks x 256 thr (4 waves), 32 rows/block. Waves = 2 M-tiles x split-K/2.
// x: reg-staged, XOR-swizzled LDS fp32, double-buffered. w1T B-frags from L2.
// ---------------------------------------------------------------------------
__global__ __launch_bounds__(256) void wn_phase1(
    const float* __restrict__ x, const ushort* __restrict__ w1T,
    const float* __restrict__ b1, const float* __restrict__ g1,
    const float* __restrict__ beta1, const float* __restrict__ w2,
    const float* __restrict__ b2, const float* __restrict__ w3,
    const float* __restrict__ b3, const float* __restrict__ g2,
    const float* __restrict__ beta2, const float* __restrict__ cpl,
    ushort* __restrict__ o_ws, float* __restrict__ gacc)
{
  __shared__ __align__(16) float lds[10816];
  float* xbuf = lds;               // 2 x [32 rows][128 k] fp32, swizzled (8192)
  float* red  = lds;               // after loop: [2][32][33] (2112, overlays xbuf)
  float* yl   = lds + 8192;        // [32][33]
  float* w2l  = lds + 9248;        // [32][16]
  float* w3l  = lds + 9760;        // [16][32]
  float* msum = lds + 10272;       // [32][17]
  const int t  = threadIdx.x;
  const int r0 = blockIdx.x * 32;

  if (t < 128) *(float4*)&w2l[t*4] = *(const float4*)&w2[t*4];
  else { const int u2 = t-128; *(float4*)&w3l[u2*4] = *(const float4*)&w3[u2*4]; }

  const int w    = t >> 6;
  const int l    = t & 63;
  const int mt   = w & 1, kh = w >> 1;
  const int lrow = l & 15, lkb = l >> 4;
  const int arow = mt*16 + lrow;
  const int aswz = arow & 7;

  f32x4 acc0 = {0.f,0.f,0.f,0.f}, acc1 = {0.f,0.f,0.f,0.f};
  float4 rg0, rg1, rg2, rg3;
  const int e0 = t, e1 = t+256, e2 = t+512, e3 = t+768;
  const int sr0 = e0>>5, su0 = e0&31, sr1 = e1>>5, su1 = e1&31;
  const int sr2 = e2>>5, su2 = e2&31, sr3 = e3>>5, su3 = e3&31;
  const int so0 = sr0*128 + (su0 ^ (sr0&7))*4;
  const int so1 = sr1*128 + (su1 ^ (sr1&7))*4;
  const int so2 = sr2*128 + (su2 ^ (sr2&7))*4;
  const int so3 = sr3*128 + (su3 ^ (sr3&7))*4;

  // prologue: stage chunk 0 into buf0
  rg0 = *(const float4*)&x[(size_t)(r0+sr0)*HID + su0*4];
  rg1 = *(const float4*)&x[(size_t)(r0+sr1)*HID + su1*4];
  rg2 = *(const float4*)&x[(size_t)(r0+sr2)*HID + su2*4];
  rg3 = *(const float4*)&x[(size_t)(r0+sr3)*HID + su3*4];
  *(float4*)&xbuf[so0] = rg0;
  *(float4*)&xbuf[so1] = rg1;
  *(float4*)&xbuf[so2] = rg2;
  *(float4*)&xbuf[so3] = rg3;

  for (int it = 0; it < 32; ++it) {
    const int cur = it & 1;
    if (it < 31) {
      const int kc = (it+1)*128;
      rg0 = *(const float4*)&x[(size_t)(r0+sr0)*HID + kc + su0*4];
      rg1 = *(const float4*)&x[(size_t)(r0+sr1)*HID + kc + su1*4];
      rg2 = *(const float4*)&x[(size_t)(r0+sr2)*HID + kc + su2*4];
      rg3 = *(const float4*)&x[(size_t)(r0+sr3)*HID + kc + su3*4];
    }
    __syncthreads();
    const float* xb = &xbuf[cur*4096];
    #pragma unroll
    for (int s = 0; s < 2; ++s) {
      const int k0 = kh*64 + s*32;
      const int ub = (k0 >> 2) + lkb*2;
      const float4 a0 = *(const float4*)&xb[arow*128 + ((ub   ^ aswz))*4];
      const float4 a1 = *(const float4*)&xb[arow*128 + (((ub+1) ^ aswz))*4];
      short8 av;
      av[0] = (short)bfc(a0.x); av[1] = (short)bfc(a0.y);
      av[2] = (short)bfc(a0.z); av[3] = (short)bfc(a0.w);
      av[4] = (short)bfc(a1.x); av[5] = (short)bfc(a1.y);
      av[6] = (short)bfc(a1.z); av[7] = (short)bfc(a1.w);
      const int kg = it*128 + k0 + lkb*8;
      const short8 bv0 = *(const short8*)&w1T[(size_t)lrow*HID + kg];
      const short8 bv1 = *(const short8*)&w1T[(size_t)(16+lrow)*HID + kg];
      acc0 = __builtin_amdgcn_mfma_f32_16x16x32_bf16(av, bv0, acc0, 0, 0, 0);
      acc1 = __builtin_amdgcn_mfma_f32_16x16x32_bf16(av, bv1, acc1, 0, 0, 0);
    }
    __syncthreads();
    if (it < 31) {
      float* xn = &xbuf[(cur^1)*4096];
      *(float4*)&xn[so0] = rg0;
      *(float4*)&xn[so1] = rg1;
      *(float4*)&xn[so2] = rg2;
      *(float4*)&xn[so3] = rg3;
    }
  }
  __syncthreads();
  // write split-K partials: C row=(lkb*4+j), col=lrow
  #pragma unroll
  for (int j = 0; j < 4; ++j) {
    red[kh*1056 + (mt*16 + lkb*4 + j)*33 + lrow]      = acc0[j];
    red[kh*1056 + (mt*16 + lkb*4 + j)*33 + 16 + lrow] = acc1[j];
  }
  __syncthreads();
  #pragma unroll
  for (int i = 0; i < 4; ++i) {
    const int e = t + i*256, row = e >> 5, col = e & 31;
    yl[row*33+col] = red[row*33+col] + red[1056 + row*33+col];
  }
  __syncthreads();
  // fused epilogue: 4 threads/row
  if (t < 128) {
    const int row = t >> 2, q = t & 3, d0 = q*8;
    float v[8]; float mu = 0.f;
    #pragma unroll
    for (int dd = 0; dd < 8; ++dd) { v[dd] = yl[row*33 + d0+dd] + b1[d0+dd]; mu += v[dd]; }
    mu += __shfl_xor(mu,1); mu += __shfl_xor(mu,2); mu *= (1.f/32.f);
    float var = 0.f;
    #pragma unroll
    for (int dd = 0; dd < 8; ++dd) { const float c = v[dd]-mu; var += c*c; }
    var += __shfl_xor(var,1); var += __shfl_xor(var,2);
    const float rs = rsqrtf(var*(1.f/32.f) + 1e-5f);
    float wiv[16];
    #pragma unroll
    for (int ww = 0; ww < 16; ++ww) wiv[ww] = 0.f;
    #pragma unroll
    for (int dd = 0; dd < 8; ++dd) {
      const float hn = (v[dd]-mu)*rs*g1[d0+dd] + beta1[d0+dd];
      const float sl = hn / (1.f + __expf(-hn));
      const float* wr = &w2l[(d0+dd)*16];
      #pragma unroll
      for (int ww = 0; ww < 16; ++ww) wiv[ww] = fmaf(sl, wr[ww], wiv[ww]);
    }
    #pragma unroll
    for (int ww = 0; ww < 16; ++ww) {
      wiv[ww] += __shfl_xor(wiv[ww],1);
      wiv[ww] += __shfl_xor(wiv[ww],2);
    }
    float mod[16];
    #pragma unroll
    for (int ww = 0; ww < 16; ++ww) mod[ww] = cpl[ww]*(1.f + wiv[ww] + b2[ww]);
    #pragma unroll
    for (int j = 0; j < 4; ++j) msum[row*17 + q*4+j] = mod[q*4+j];
    float p[8];
    #pragma unroll
    for (int dd = 0; dd < 8; ++dd) p[dd] = b3[d0+dd];
    #pragma unroll
    for (int ww = 0; ww < 16; ++ww) {
      const float m = mod[ww];
      const float* wr = &w3l[ww*32 + d0];
      #pragma unroll
      for (int dd = 0; dd < 8; ++dd) p[dd] = fmaf(m, wr[dd], p[dd]);
    }
    float mu2 = 0.f;
    #pragma unroll
    for (int dd = 0; dd < 8; ++dd) mu2 += p[dd];
    mu2 += __shfl_xor(mu2,1); mu2 += __shfl_xor(mu2,2); mu2 *= (1.f/32.f);
    float var2 = 0.f;
    #pragma unroll
    for (int dd = 0; dd < 8; ++dd) { const float c = p[dd]-mu2; var2 += c*c; }
    var2 += __shfl_xor(var2,1); var2 += __shfl_xor(var2,2);
    const float rs2 = rsqrtf(var2*(1.f/32.f) + 1e-5f);
    ushort8 ov;
    #pragma unroll
    for (int dd = 0; dd < 8; ++dd) {
      const float hn = (p[dd]-mu2)*rs2*g2[d0+dd] + beta2[d0+dd];
      ov[dd] = bfc(hn / (1.f + __expf(-hn)));
    }
    *(ushort8*)&o_ws[(size_t)(r0+row)*32 + d0] = ov;
  }
  __syncthreads();
  if (t < 16) {
    float s = 0.f;
    for (int r = 0; r < 32; ++r) s += msum[r*17 + t];
    atomicAdd(gacc + t, s);
  }
}

// ---------------------------------------------------------------------------
// Phase 2: resonance_factor -> cpl[16]
// ---------------------------------------------------------------------------
__global__ void wn_phase2(const float* __restrict__ gacc, float* __restrict__ cpl)
{
  __shared__ float res[16];
  const int t = threadIdx.x;
  if (t < 16) res[t] = 0.1f * fabsf(gacc[t] * (1.f/(float)R_TOTAL));
  __syncthreads();
  if (t == 0) {
    float s = 0.f;
    #pragma unroll
    for (int ww = 0; ww < 16; ++ww) s += res[ww];
    cpl[16] = 1.f / (1.f + expf(-s*(1.f/16.f)));
  }
}

// ---------------------------------------------------------------------------
// Phase 3 v3 (MFMA swapped-operand, zero LDS, EXPLICIT 4-wide pipeline):
// out = x + rf*(o@w4 + b4). Named registers force 8 loads in flight per
// group (w4T x4 + x x4), fine-grained vmcnt instead of per-iter drain.
// Nontemporal on x/out (streamed once) keeps w4T/o hot in L2.
// 2048 blocks (256 row-blks x 8 strips) x 256 thr; wave = one 16-row m-tile.
// ---------------------------------------------------------------------------
__global__ __launch_bounds__(256) void wn_phase3(
    const float* __restrict__ x, const ushort* __restrict__ o_bf,
    const ushort* __restrict__ w4T, const float* __restrict__ b4,
    const float* __restrict__ cpl, float* __restrict__ out)
{
  const int t = threadIdx.x, l = t & 63, w = t >> 6;
  const int bid = blockIdx.x;
  const int strip = bid & 7, m0 = (bid >> 3) * 64 + w*16;
  const float rf = cpl[16];
  const int lm = l & 15, lkb = l >> 4;
  // B-frag: o rows (col operand, m)
  const short8 bv = *(const short8*)&o_bf[(size_t)(m0+lm)*32 + lkb*8];
  const int mrow = m0 + lm;
  const size_t rowbase = (size_t)mrow*HID + strip*512 + lkb*4;
  const ushort* wp = &w4T[(size_t)(strip*512 + lm)*32 + lkb*8];
  const float* b4p = &b4[strip*512 + lkb*4];

  for (int g = 0; g < 8; ++g) {
    const int nb = g*64;               // 4 n-tiles of 16 per group
    // --- issue all 8 global loads back-to-back (named regs) ---
    const short8 av0 = *(const short8*)(wp + (size_t)(nb+ 0)*32);
    const short8 av1 = *(const short8*)(wp + (size_t)(nb+16)*32);
    const short8 av2 = *(const short8*)(wp + (size_t)(nb+32)*32);
    const short8 av3 = *(const short8*)(wp + (size_t)(nb+48)*32);
    const f32x4 xv0 = __builtin_nontemporal_load((const f32x4*)&x[rowbase + nb +  0]);
    const f32x4 xv1 = __builtin_nontemporal_load((const f32x4*)&x[rowbase + nb + 16]);
    const f32x4 xv2 = __builtin_nontemporal_load((const f32x4*)&x[rowbase + nb + 32]);
    const f32x4 xv3 = __builtin_nontemporal_load((const f32x4*)&x[rowbase + nb + 48]);
    const f32x4 bq0 = *(const f32x4*)&b4p[nb +  0];
    const f32x4 bq1 = *(const f32x4*)&b4p[nb + 16];
    const f32x4 bq2 = *(const f32x4*)&b4p[nb + 32];
    const f32x4 bq3 = *(const f32x4*)&b4p[nb + 48];
    // --- 4 independent MFMAs ---
    f32x4 c0 = {0.f,0.f,0.f,0.f}, c1 = {0.f,0.f,0.f,0.f};
    f32x4 c2 = {0.f,0.f,0.f,0.f}, c3 = {0.f,0.f,0.f,0.f};
    c0 = __builtin_amdgcn_mfma_f32_16x16x32_bf16(av0, bv, c0, 0, 0, 0);
    c1 = __builtin_amdgcn_mfma_f32_16x16x32_bf16(av1, bv, c1, 0, 0, 0);
    c2 = __builtin_amdgcn_mfma_f32_16x16x32_bf16(av2, bv, c2, 0, 0, 0);
    c3 = __builtin_amdgcn_mfma_f32_16x16x32_bf16(av3, bv, c3, 0, 0, 0);
    // --- epilogue + 4 stores ---
    f32x4 s0, s1, s2, s3;
    #pragma unroll
    for (int j = 0; j < 4; ++j) {
      s0[j] = fmaf(rf, c0[j]+bq0[j], xv0[j]);
      s1[j] = fmaf(rf, c1[j]+bq1[j], xv1[j]);
      s2[j] = fmaf(rf, c2[j]+bq2[j], xv2[j]);
      s3[j] = fmaf(rf, c3[j]+bq3[j], xv3[j]);
    }
    __builtin_nontemporal_store(s0, (f32x4*)&out[rowbase + nb +  0]);
    __builtin_nontemporal_store(s1, (f32x4*)&out[rowbase + nb + 16]);
    __builtin_nontemporal_store(s2, (f32x4*)&out[rowbase + nb + 32]);
    __builtin_nontemporal_store(s3, (f32x4*)&out[rowbase + nb + 48]);
  }
}

extern "C" void kernel_launch(void* const* d_in, const int* in_sizes, int n_in,
                              void* d_out, int out_size, void* d_ws, size_t ws_size,
                              hipStream_t stream) {
  const float* x        = (const float*)d_in[0];
  const float* freq     = (const float*)d_in[1];
  const float* phases   = (const float*)d_in[2];
  const float* coupling = (const float*)d_in[3];
  const float* damping  = (const float*)d_in[4];
  const float* w1       = (const float*)d_in[5];
  const float* b1       = (const float*)d_in[6];
  const float* g1       = (const float*)d_in[7];
  const float* beta1    = (const float*)d_in[8];
  const float* w2       = (const float*)d_in[9];
  const float* b2       = (const float*)d_in[10];
  const float* w3       = (const float*)d_in[11];
  const float* b3       = (const float*)d_in[12];
  const float* g2       = (const float*)d_in[13];
  const float* beta2    = (const float*)d_in[14];
  const float* w4       = (const float*)d_in[15];
  const float* b4       = (const float*)d_in[16];
  const float* tstep    = (const float*)d_in[17];
  float* out = (float*)d_out;

  char* wsb = (char*)d_ws;
  ushort* o_bf = (ushort*)wsb;                        // 1 MiB
  ushort* w1T  = (ushort*)(wsb + (1<<20));            // 256 KiB
  ushort* w4T  = (ushort*)(wsb + (1<<20) + (256<<10));// 256 KiB
  float*  gacc = (float*)(wsb + (1<<20) + (512<<10)); // 64 B
  float*  cpl  = gacc + 16;                           // 17 floats

  hipMemsetAsync(gacc, 0, 16*sizeof(float), stream);
  hipLaunchKernelGGL(wn_prep, dim3(129), dim3(256), 0, stream,
                     w1, w4, w1T, w4T, freq, phases, coupling, damping, tstep, cpl);
  hipLaunchKernelGGL(wn_phase1, dim3(512), dim3(256), 0, stream,
                     x, w1T, b1, g1, beta1, w2, b2, w3, b3, g2, beta2, cpl, o_bf, gacc);
  hipLaunchKernelGGL(wn_phase2, dim3(1), dim3(64), 0, stream, gacc, cpl);
  hipLaunchKernelGGL(wn_phase3, dim3(2048), dim3(256), 0, stream,
                     x, o_bf, w4T, b4, cpl, out);
}

// Round 8
// 187.145 us; speedup vs baseline: 1.3645x; 1.2162x over previous
//
#include <hip/hip_runtime.h>
#include <hip/hip_bf16.h>
#include <math.h>

#define HID 4096
#define R_TOTAL 16384

typedef __attribute__((ext_vector_type(8))) short short8;
typedef __attribute__((ext_vector_type(8))) unsigned short ushort8;
typedef __attribute__((ext_vector_type(4))) float f32x4;

__device__ __forceinline__ ushort bfc(float f) {
  __hip_bfloat16 h = __float2bfloat16(f);
  return *(ushort*)&h;
}

// ---------------------------------------------------------------------------
// Prep: w1T bf16 [32][4096] (col-major of w1), w4T bf16 [4096][32]
// (transpose of w4), and coupled[16] -> cpl[0..15].
// ---------------------------------------------------------------------------
__global__ __launch_bounds__(256) void wn_prep(
    const float* __restrict__ w1, const float* __restrict__ w4,
    ushort* __restrict__ w1T, ushort* __restrict__ w4T,
    const float* __restrict__ freq, const float* __restrict__ phases,
    const float* __restrict__ coupling, const float* __restrict__ damping,
    const float* __restrict__ tstep, float* __restrict__ cpl)
{
  __shared__ ushort tile[64*72];
  __shared__ float base[16];
  const int b = blockIdx.x, t = threadIdx.x;
  if (b < 64) {                      // w1T chunk: k in [b*64, b*64+64)
    #pragma unroll
    for (int i = 0; i < 8; ++i) {
      const int e = t + i*256, kk = e >> 5, c = e & 31;
      tile[c*72 + kk] = bfc(w1[(size_t)(b*64+kk)*32 + c]);
    }
    __syncthreads();
    const int c = t >> 3, j = t & 7;
    ushort8 v;
    #pragma unroll
    for (int q = 0; q < 8; ++q) v[q] = tile[c*72 + j*8 + q];
    *(ushort8*)&w1T[(size_t)c*HID + b*64 + j*8] = v;
  } else if (b < 128) {              // w4T chunk: h in [b2*64, b2*64+64)
    const int b2 = b - 64;
    #pragma unroll
    for (int i = 0; i < 8; ++i) {
      const int e = t + i*256, d = e >> 6, hh = e & 63;
      tile[hh*40 + d] = bfc(w4[(size_t)d*HID + b2*64 + hh]);
    }
    __syncthreads();
    const int hh = t >> 2, j = t & 3;
    ushort8 v;
    #pragma unroll
    for (int q = 0; q < 8; ++q) v[q] = tile[hh*40 + j*8 + q];
    *(ushort8*)&w4T[(size_t)(b2*64+hh)*32 + j*8] = v;
  } else {                           // coupled
    const float tt = tstep[0] + 0.1f;
    if (t < 16)
      base[t] = sinf(6.283185307179586f*freq[t]*tt + phases[t]) * expf(-damping[t]*tt);
    __syncthreads();
    if (t < 16) {
      float s = 0.f;
      #pragma unroll
      for (int i = 0; i < 16; ++i) s += base[i]*coupling[i*16+t];
      cpl[t] = tanhf(s);
    }
  }
}

// ---------------------------------------------------------------------------
// Phase 1 v3 (bf16-LDS MFMA): x@w1 -> LN -> SiLU -> @w2 -> mod -> @w3
//   -> LN -> SiLU -> o(bf16).
// 512 blocks x 256 thr (4 waves), 32 rows/block; waves = 2 m-tiles x split-K/2.
// x converted to bf16 AT STAGING (register-side cvt), stored to granule-XOR
// swizzled LDS (16KB dbuf -> ~5 blocks/CU). Inner loop: 1 ds_read_b128 per
// A-frag, zero repack. w1T B-frags from L2. Double-buffered, write-late.
// ---------------------------------------------------------------------------
__global__ __launch_bounds__(256) void wn_phase1(
    const float* __restrict__ x, const ushort* __restrict__ w1T,
    const float* __restrict__ b1, const float* __restrict__ g1,
    const float* __restrict__ beta1, const float* __restrict__ w2,
    const float* __restrict__ b2, const float* __restrict__ w3,
    const float* __restrict__ b3, const float* __restrict__ g2,
    const float* __restrict__ beta2, const float* __restrict__ cpl,
    ushort* __restrict__ o_ws, float* __restrict__ gacc)
{
  __shared__ __align__(16) float lds[6720];
  ushort* xb  = (ushort*)lds;      // 2 x [32 rows][16 granules x 8 bf16] (16KB)
  float* red  = lds;               // overlay after K-loop: [2][32][33] = 2112
  float* yl   = lds + 4096;        // [32][33]
  float* w2l  = lds + 5152;        // [32][16]
  float* w3l  = lds + 5664;        // [16][32]
  float* msum = lds + 6176;        // [32][17]
  const int t  = threadIdx.x;
  const int r0 = blockIdx.x * 32;

  if (t < 128) *(float4*)&w2l[t*4] = *(const float4*)&w2[t*4];
  else { const int u2 = t-128; *(float4*)&w3l[u2*4] = *(const float4*)&w3[u2*4]; }

  // staging mapping: thread -> (row, 16-float chunk)
  const int srow = t >> 3, sc = t & 7;
  const int wg0   = ((sc*2) ^ ((srow&7)<<1));          // physical granule
  const int wbase = srow*128 + wg0*8;                  // ushort offset in buffer
  const float* xp = &x[(size_t)(r0+srow)*HID + sc*16];

  // MFMA mapping
  const int w    = t >> 6, l = t & 63;
  const int mt   = w & 1, kh = w >> 1;
  const int lrow = l & 15, lkb = l >> 4;
  const int arow = mt*16 + lrow;
  const int rsw  = (arow&7) << 1;
  const int ra_s0 = arow*128 + ((kh*8 +     lkb) ^ rsw)*8;  // s=0 frag addr
  const int ra_s1 = arow*128 + ((kh*8 + 4 + lkb) ^ rsw)*8;  // s=1 frag addr
  const ushort* bp0 = &w1T[(size_t)lrow*HID + kh*64 + lkb*8];
  const ushort* bp1 = bp0 + 16*HID;

  f32x4 acc0 = {0.f,0.f,0.f,0.f}, acc1 = {0.f,0.f,0.f,0.f};
  float4 rg0, rg1, rg2, rg3;

  // prologue: stage chunk 0 into buf0
  rg0 = *(const float4*)&xp[0];
  rg1 = *(const float4*)&xp[4];
  rg2 = *(const float4*)&xp[8];
  rg3 = *(const float4*)&xp[12];
  {
    ushort8 v0, v1;
    v0[0]=bfc(rg0.x); v0[1]=bfc(rg0.y); v0[2]=bfc(rg0.z); v0[3]=bfc(rg0.w);
    v0[4]=bfc(rg1.x); v0[5]=bfc(rg1.y); v0[6]=bfc(rg1.z); v0[7]=bfc(rg1.w);
    v1[0]=bfc(rg2.x); v1[1]=bfc(rg2.y); v1[2]=bfc(rg2.z); v1[3]=bfc(rg2.w);
    v1[4]=bfc(rg3.x); v1[5]=bfc(rg3.y); v1[6]=bfc(rg3.z); v1[7]=bfc(rg3.w);
    *(ushort8*)&xb[wbase]     = v0;
    *(ushort8*)&xb[wbase + 8] = v1;
  }

  for (int it = 0; it < 32; ++it) {
    const int cur = it & 1;
    if (it < 31) {
      const int kc = (it+1)*128;
      rg0 = *(const float4*)&xp[kc];
      rg1 = *(const float4*)&xp[kc + 4];
      rg2 = *(const float4*)&xp[kc + 8];
      rg3 = *(const float4*)&xp[kc + 12];
    }
    __syncthreads();
    {
      const ushort* xc = &xb[cur*4096];
      const int kg = it*128;
      const short8 av0 = *(const short8*)&xc[ra_s0];
      const short8 bv00 = *(const short8*)(bp0 + kg);
      const short8 bv01 = *(const short8*)(bp1 + kg);
      acc0 = __builtin_amdgcn_mfma_f32_16x16x32_bf16(av0, bv00, acc0, 0, 0, 0);
      acc1 = __builtin_amdgcn_mfma_f32_16x16x32_bf16(av0, bv01, acc1, 0, 0, 0);
      const short8 av1 = *(const short8*)&xc[ra_s1];
      const short8 bv10 = *(const short8*)(bp0 + kg + 32);
      const short8 bv11 = *(const short8*)(bp1 + kg + 32);
      acc0 = __builtin_amdgcn_mfma_f32_16x16x32_bf16(av1, bv10, acc0, 0, 0, 0);
      acc1 = __builtin_amdgcn_mfma_f32_16x16x32_bf16(av1, bv11, acc1, 0, 0, 0);
    }
    __syncthreads();
    if (it < 31) {
      ushort* xn = &xb[(cur^1)*4096];
      ushort8 v0, v1;
      v0[0]=bfc(rg0.x); v0[1]=bfc(rg0.y); v0[2]=bfc(rg0.z); v0[3]=bfc(rg0.w);
      v0[4]=bfc(rg1.x); v0[5]=bfc(rg1.y); v0[6]=bfc(rg1.z); v0[7]=bfc(rg1.w);
      v1[0]=bfc(rg2.x); v1[1]=bfc(rg2.y); v1[2]=bfc(rg2.z); v1[3]=bfc(rg2.w);
      v1[4]=bfc(rg3.x); v1[5]=bfc(rg3.y); v1[6]=bfc(rg3.z); v1[7]=bfc(rg3.w);
      *(ushort8*)&xn[wbase]     = v0;
      *(ushort8*)&xn[wbase + 8] = v1;
    }
  }
  __syncthreads();
  // write split-K partials: C row=(lkb*4+j), col=lrow
  #pragma unroll
  for (int j = 0; j < 4; ++j) {
    red[kh*1056 + (mt*16 + lkb*4 + j)*33 + lrow]      = acc0[j];
    red[kh*1056 + (mt*16 + lkb*4 + j)*33 + 16 + lrow] = acc1[j];
  }
  __syncthreads();
  #pragma unroll
  for (int i = 0; i < 4; ++i) {
    const int e = t + i*256, row = e >> 5, col = e & 31;
    yl[row*33+col] = red[row*33+col] + red[1056 + row*33+col];
  }
  __syncthreads();
  // fused epilogue: 4 threads/row
  if (t < 128) {
    const int row = t >> 2, q = t & 3, d0 = q*8;
    float v[8]; float mu = 0.f;
    #pragma unroll
    for (int dd = 0; dd < 8; ++dd) { v[dd] = yl[row*33 + d0+dd] + b1[d0+dd]; mu += v[dd]; }
    mu += __shfl_xor(mu,1); mu += __shfl_xor(mu,2); mu *= (1.f/32.f);
    float var = 0.f;
    #pragma unroll
    for (int dd = 0; dd < 8; ++dd) { const float c = v[dd]-mu; var += c*c; }
    var += __shfl_xor(var,1); var += __shfl_xor(var,2);
    const float rs = rsqrtf(var*(1.f/32.f) + 1e-5f);
    float wiv[16];
    #pragma unroll
    for (int ww = 0; ww < 16; ++ww) wiv[ww] = 0.f;
    #pragma unroll
    for (int dd = 0; dd < 8; ++dd) {
      const float hn = (v[dd]-mu)*rs*g1[d0+dd] + beta1[d0+dd];
      const float sl = hn / (1.f + __expf(-hn));
      const float* wr = &w2l[(d0+dd)*16];
      #pragma unroll
      for (int ww = 0; ww < 16; ++ww) wiv[ww] = fmaf(sl, wr[ww], wiv[ww]);
    }
    #pragma unroll
    for (int ww = 0; ww < 16; ++ww) {
      wiv[ww] += __shfl_xor(wiv[ww],1);
      wiv[ww] += __shfl_xor(wiv[ww],2);
    }
    float mod[16];
    #pragma unroll
    for (int ww = 0; ww < 16; ++ww) mod[ww] = cpl[ww]*(1.f + wiv[ww] + b2[ww]);
    #pragma unroll
    for (int j = 0; j < 4; ++j) msum[row*17 + q*4+j] = mod[q*4+j];
    float p[8];
    #pragma unroll
    for (int dd = 0; dd < 8; ++dd) p[dd] = b3[d0+dd];
    #pragma unroll
    for (int ww = 0; ww < 16; ++ww) {
      const float m = mod[ww];
      const float* wr = &w3l[ww*32 + d0];
      #pragma unroll
      for (int dd = 0; dd < 8; ++dd) p[dd] = fmaf(m, wr[dd], p[dd]);
    }
    float mu2 = 0.f;
    #pragma unroll
    for (int dd = 0; dd < 8; ++dd) mu2 += p[dd];
    mu2 += __shfl_xor(mu2,1); mu2 += __shfl_xor(mu2,2); mu2 *= (1.f/32.f);
    float var2 = 0.f;
    #pragma unroll
    for (int dd = 0; dd < 8; ++dd) { const float c = p[dd]-mu2; var2 += c*c; }
    var2 += __shfl_xor(var2,1); var2 += __shfl_xor(var2,2);
    const float rs2 = rsqrtf(var2*(1.f/32.f) + 1e-5f);
    ushort8 ov;
    #pragma unroll
    for (int dd = 0; dd < 8; ++dd) {
      const float hn = (p[dd]-mu2)*rs2*g2[d0+dd] + beta2[d0+dd];
      ov[dd] = bfc(hn / (1.f + __expf(-hn)));
    }
    *(ushort8*)&o_ws[(size_t)(r0+row)*32 + d0] = ov;
  }
  __syncthreads();
  if (t < 16) {
    float s = 0.f;
    for (int r = 0; r < 32; ++r) s += msum[r*17 + t];
    atomicAdd(gacc + t, s);
  }
}

// ---------------------------------------------------------------------------
// Phase 2: resonance_factor -> cpl[16]
// ---------------------------------------------------------------------------
__global__ void wn_phase2(const float* __restrict__ gacc, float* __restrict__ cpl)
{
  __shared__ float res[16];
  const int t = threadIdx.x;
  if (t < 16) res[t] = 0.1f * fabsf(gacc[t] * (1.f/(float)R_TOTAL));
  __syncthreads();
  if (t == 0) {
    float s = 0.f;
    #pragma unroll
    for (int ww = 0; ww < 16; ++ww) s += res[ww];
    cpl[16] = 1.f / (1.f + expf(-s*(1.f/16.f)));
  }
}

// ---------------------------------------------------------------------------
// Phase 3 v4 (R4 unroll-2 swapped-operand + REVERSED row order + nt stores):
// out = x + rf*(o@w4 + b4). Phase1 streamed x ascending, so descending rows
// harvest x's L3-resident tail; nt stores don't pollute L3 with out.
// 2048 blocks (256 row-blks x 8 strips) x 256 thr; wave = one 16-row m-tile.
// ---------------------------------------------------------------------------
__global__ __launch_bounds__(256) void wn_phase3(
    const float* __restrict__ x, const ushort* __restrict__ o_bf,
    const ushort* __restrict__ w4T, const float* __restrict__ b4,
    const float* __restrict__ cpl, float* __restrict__ out)
{
  const int t = threadIdx.x, l = t & 63, w = t >> 6;
  const int bid = blockIdx.x;
  const int strip = bid & 7;
  const int m0 = (255 - (bid >> 3)) * 64 + w*16;   // reversed row order
  const float rf = cpl[16];
  const int lm = l & 15, lkb = l >> 4;
  // B-frag: o rows (col operand, m): col=lane&15, k=(lane>>4)*8..+7
  const short8 bv = *(const short8*)&o_bf[(size_t)(m0+lm)*32 + lkb*8];
  const int mrow = m0 + lm;            // this lane's output row
  const size_t rowbase = (size_t)mrow*HID + strip*512 + lkb*4;
  #pragma unroll 2
  for (int nt = 0; nt < 32; ++nt) {
    const int n0 = strip*512 + nt*16;
    // A-frag: w4T rows (row operand, n): row=lane&15, k=(lane>>4)*8..+7
    const short8 av = *(const short8*)&w4T[(size_t)(n0+lm)*32 + lkb*8];
    f32x4 c = {0.f,0.f,0.f,0.f};
    c = __builtin_amdgcn_mfma_f32_16x16x32_bf16(av, bv, c, 0, 0, 0);
    // lane owns C rows n0+lkb*4..+3 (consecutive n), col m = mrow
    const size_t off = rowbase + (size_t)nt*16;
    const float4 xv  = *(const float4*)&x[off];
    const float4 b4v = *(const float4*)&b4[n0 + lkb*4];
    f32x4 o2;
    o2[0] = fmaf(rf, c[0] + b4v.x, xv.x);
    o2[1] = fmaf(rf, c[1] + b4v.y, xv.y);
    o2[2] = fmaf(rf, c[2] + b4v.z, xv.z);
    o2[3] = fmaf(rf, c[3] + b4v.w, xv.w);
    __builtin_nontemporal_store(o2, (f32x4*)&out[off]);
  }
}

extern "C" void kernel_launch(void* const* d_in, const int* in_sizes, int n_in,
                              void* d_out, int out_size, void* d_ws, size_t ws_size,
                              hipStream_t stream) {
  const float* x        = (const float*)d_in[0];
  const float* freq     = (const float*)d_in[1];
  const float* phases   = (const float*)d_in[2];
  const float* coupling = (const float*)d_in[3];
  const float* damping  = (const float*)d_in[4];
  const float* w1       = (const float*)d_in[5];
  const float* b1       = (const float*)d_in[6];
  const float* g1       = (const float*)d_in[7];
  const float* beta1    = (const float*)d_in[8];
  const float* w2       = (const float*)d_in[9];
  const float* b2       = (const float*)d_in[10];
  const float* w3       = (const float*)d_in[11];
  const float* b3       = (const float*)d_in[12];
  const float* g2       = (const float*)d_in[13];
  const float* beta2    = (const float*)d_in[14];
  const float* w4       = (const float*)d_in[15];
  const float* b4       = (const float*)d_in[16];
  const float* tstep    = (const float*)d_in[17];
  float* out = (float*)d_out;

  char* wsb = (char*)d_ws;
  ushort* o_bf = (ushort*)wsb;                        // 1 MiB
  ushort* w1T  = (ushort*)(wsb + (1<<20));            // 256 KiB
  ushort* w4T  = (ushort*)(wsb + (1<<20) + (256<<10));// 256 KiB
  float*  gacc = (float*)(wsb + (1<<20) + (512<<10)); // 64 B
  float*  cpl  = gacc + 16;                           // 17 floats

  hipMemsetAsync(gacc, 0, 16*sizeof(float), stream);
  hipLaunchKernelGGL(wn_prep, dim3(129), dim3(256), 0, stream,
                     w1, w4, w1T, w4T, freq, phases, coupling, damping, tstep, cpl);
  hipLaunchKernelGGL(wn_phase1, dim3(512), dim3(256), 0, stream,
                     x, w1T, b1, g1, beta1, w2, b2, w3, b3, g2, beta2, cpl, o_bf, gacc);
  hipLaunchKernelGGL(wn_phase2, dim3(1), dim3(64), 0, stream, gacc, cpl);
  hipLaunchKernelGGL(wn_phase3, dim3(2048), dim3(256), 0, stream,
                     x, o_bf, w4T, b4, cpl, out);
}